// Round 2
// baseline (3919.796 us; speedup 1.0000x reference)
//
#include <hip/hip_runtime.h>
#include <math.h>

#define B_ 128
#define N_ 100
#define E_ 100
#define D_ 64
#define EH 50        // e (or n) half handled per block
#define PAD 68       // f32 row pad for [*,D] tiles (bytes: 272)
#define SP 52        // score-matrix row pad (f32)
#define KP 56        // mask row pad (bytes, 8-aligned)
#define LALPHA 0.2f
#define NEGV -9e15f

// ---------------------------------------------------------------------------
// node -> edge: one block per (b, e-half). 512 threads.
//   ec[e,d]   = sum_n (H[b,n,e]>0) h[n,d]
//   S_k[n,e]  = sum_d h[n,d]*ec[e,d]*a_k[d];  S = select(k(n,e)); leaky; NEG
//   alpha     = softmax_n(S)
//   edge[e,d] = sum_n alpha[n,e] h[n,d]
// ---------------------------------------------------------------------------
__global__ __launch_bounds__(512) void k_n2e(
    const float* __restrict__ h,   // (B,N,D)
    const float* __restrict__ Hm,  // (B,N,E)
    const float* __restrict__ a0,
    const float* __restrict__ a1,
    const float* __restrict__ a2,
    float* __restrict__ edge)      // (B,E,D)
{
    __shared__ float sh_h[N_ * PAD];          // [n][d]
    __shared__ float sh_ec[EH * PAD];         // [le][d]
    __shared__ float sh_S[N_ * SP];           // [n][le] scores then P
    __shared__ unsigned char sh_k[N_ * KP];   // [n][le]
    __shared__ float sh_a[3 * PAD];
    __shared__ float sh_inv[EH];

    const int b = blockIdx.y, eh = blockIdx.x;
    const int e_base = eh * EH;
    const int tid = threadIdx.x;

    // ---- stage h (float4, coalesced) ----
    for (int i4 = tid; i4 < N_ * D_ / 4; i4 += 512) {
        const float4 v = *reinterpret_cast<const float4*>(&h[b * N_ * D_ + i4 * 4]);
        const int n = i4 >> 4, dq = i4 & 15;
        *reinterpret_cast<float4*>(&sh_h[n * PAD + dq * 4]) = v;
    }
    // ---- stage a ----
    if (tid < 192) {
        const int k = tid >> 6, d = tid & 63;
        const float* ap = (k == 0) ? a0 : (k == 1) ? a1 : a2;
        sh_a[k * PAD + d] = ap[d];
    }
    // ---- stage masks (coalesced in e) ----
    for (int i = tid; i < N_ * EH; i += 512) {
        const int n = i / EH, le = i % EH;
        sh_k[n * KP + le] = (unsigned char)Hm[(b * N_ + n) * E_ + e_base + le];
    }
    __syncthreads();

    // ---- ec phase: tile (4e,8d), n split over 4 adjacent lanes ----
    if (tid < 416) {
        const int ng = tid & 3, tile = tid >> 2;   // tile 0..103
        const int e0 = (tile / 8) * 4, d0 = (tile & 7) * 8;
        float acc[4][8];
        #pragma unroll
        for (int i = 0; i < 4; ++i)
            #pragma unroll
            for (int j = 0; j < 8; ++j) acc[i][j] = 0.f;
        for (int n = ng * 25; n < ng * 25 + 25; ++n) {
            const unsigned int mw = *reinterpret_cast<const unsigned int*>(&sh_k[n * KP + e0]);
            const float4 h0 = *reinterpret_cast<const float4*>(&sh_h[n * PAD + d0]);
            const float4 h1 = *reinterpret_cast<const float4*>(&sh_h[n * PAD + d0 + 4]);
            const float hv[8] = {h0.x, h0.y, h0.z, h0.w, h1.x, h1.y, h1.z, h1.w};
            #pragma unroll
            for (int i = 0; i < 4; ++i) {
                const float m = ((mw >> (8 * i)) & 255u) ? 1.f : 0.f;
                #pragma unroll
                for (int j = 0; j < 8; ++j) acc[i][j] += m * hv[j];
            }
        }
        #pragma unroll
        for (int i = 0; i < 4; ++i)
            #pragma unroll
            for (int j = 0; j < 8; ++j) {
                float v = acc[i][j];
                v += __shfl_xor(v, 1);
                v += __shfl_xor(v, 2);
                acc[i][j] = v;
            }
        if (ng == 0) {
            #pragma unroll
            for (int i = 0; i < 4; ++i)
                if (e0 + i < EH) {
                    *reinterpret_cast<float4*>(&sh_ec[(e0 + i) * PAD + d0]) =
                        make_float4(acc[i][0], acc[i][1], acc[i][2], acc[i][3]);
                    *reinterpret_cast<float4*>(&sh_ec[(e0 + i) * PAD + d0 + 4]) =
                        make_float4(acc[i][4], acc[i][5], acc[i][6], acc[i][7]);
                }
        }
    }
    __syncthreads();

    // ---- score phase: tile (4n,5e), 3 k's at once ----
    if (tid < 250) {
        const int n0 = (tid / 10) * 4, le0 = (tid % 10) * 5;
        float acc[3][4][5];
        #pragma unroll
        for (int k = 0; k < 3; ++k)
            #pragma unroll
            for (int i = 0; i < 4; ++i)
                #pragma unroll
                for (int j = 0; j < 5; ++j) acc[k][i][j] = 0.f;
        #pragma unroll
        for (int s = 0; s < 16; ++s) {
            const int d0 = s * 4;
            float4 hv[4], ev[5], av[3];
            #pragma unroll
            for (int i = 0; i < 4; ++i)
                hv[i] = *reinterpret_cast<const float4*>(&sh_h[(n0 + i) * PAD + d0]);
            #pragma unroll
            for (int j = 0; j < 5; ++j)
                ev[j] = *reinterpret_cast<const float4*>(&sh_ec[(le0 + j) * PAD + d0]);
            #pragma unroll
            for (int k = 0; k < 3; ++k)
                av[k] = *reinterpret_cast<const float4*>(&sh_a[k * PAD + d0]);
            #pragma unroll
            for (int k = 0; k < 3; ++k)
                #pragma unroll
                for (int j = 0; j < 5; ++j) {
                    const float wx = ev[j].x * av[k].x, wy = ev[j].y * av[k].y;
                    const float wz = ev[j].z * av[k].z, ww = ev[j].w * av[k].w;
                    #pragma unroll
                    for (int i = 0; i < 4; ++i)
                        acc[k][i][j] += hv[i].x * wx + hv[i].y * wy + hv[i].z * wz + hv[i].w * ww;
                }
        }
        #pragma unroll
        for (int i = 0; i < 4; ++i)
            #pragma unroll
            for (int j = 0; j < 5; ++j) {
                const int kk = sh_k[(n0 + i) * KP + le0 + j];
                const float v = (kk == 1) ? acc[0][i][j] : (kk == 2) ? acc[1][i][j] : acc[2][i][j];
                const float lv = (v >= 0.f) ? v : LALPHA * v;
                sh_S[(n0 + i) * SP + le0 + j] = (kk == 0) ? NEGV : lv;
            }
    }
    __syncthreads();

    // ---- softmax over n (rows), per le column: 8 lanes per column ----
    if (tid < 400) {
        const int le = tid >> 3, g = tid & 7;
        float mx = -INFINITY;
        for (int n = g; n < N_; n += 8) mx = fmaxf(mx, sh_S[n * SP + le]);
        mx = fmaxf(mx, __shfl_xor(mx, 1));
        mx = fmaxf(mx, __shfl_xor(mx, 2));
        mx = fmaxf(mx, __shfl_xor(mx, 4));
        float sum = 0.f;
        for (int n = g; n < N_; n += 8) {
            const float p = __expf(sh_S[n * SP + le] - mx);
            sh_S[n * SP + le] = p;
            sum += p;
        }
        sum += __shfl_xor(sum, 1);
        sum += __shfl_xor(sum, 2);
        sum += __shfl_xor(sum, 4);
        if (g == 0) sh_inv[le] = 1.f / sum;
    }
    __syncthreads();

    // ---- weighted sum: edge[e,d] = inv[e]*sum_n P[n,e] h[n,d]; tile (4e,8d), n-split 4 ----
    if (tid < 416) {
        const int ng = tid & 3, tile = tid >> 2;
        const int e0 = (tile / 8) * 4, d0 = (tile & 7) * 8;
        float acc[4][8];
        #pragma unroll
        for (int i = 0; i < 4; ++i)
            #pragma unroll
            for (int j = 0; j < 8; ++j) acc[i][j] = 0.f;
        for (int n = ng * 25; n < ng * 25 + 25; ++n) {
            const float4 p = *reinterpret_cast<const float4*>(&sh_S[n * SP + e0]);
            const float4 h0 = *reinterpret_cast<const float4*>(&sh_h[n * PAD + d0]);
            const float4 h1 = *reinterpret_cast<const float4*>(&sh_h[n * PAD + d0 + 4]);
            const float pv[4] = {p.x, p.y, p.z, p.w};
            const float hv[8] = {h0.x, h0.y, h0.z, h0.w, h1.x, h1.y, h1.z, h1.w};
            #pragma unroll
            for (int i = 0; i < 4; ++i)
                #pragma unroll
                for (int j = 0; j < 8; ++j) acc[i][j] += pv[i] * hv[j];
        }
        #pragma unroll
        for (int i = 0; i < 4; ++i)
            #pragma unroll
            for (int j = 0; j < 8; ++j) {
                float v = acc[i][j];
                v += __shfl_xor(v, 1);
                v += __shfl_xor(v, 2);
                acc[i][j] = v;
            }
        if (ng == 0) {
            #pragma unroll
            for (int i = 0; i < 4; ++i)
                if (e0 + i < EH) {
                    const float inv = sh_inv[e0 + i];
                    float* dst = &edge[(b * E_ + e_base + e0 + i) * D_ + d0];
                    *reinterpret_cast<float4*>(dst) =
                        make_float4(acc[i][0] * inv, acc[i][1] * inv, acc[i][2] * inv, acc[i][3] * inv);
                    *reinterpret_cast<float4*>(dst + 4) =
                        make_float4(acc[i][4] * inv, acc[i][5] * inv, acc[i][6] * inv, acc[i][7] * inv);
                }
        }
    }
}

// ---------------------------------------------------------------------------
// edge -> node: one block per (b, n-half). 512 threads.
//   ht[n,d]    = h[n,d] + s_c[d]
//   T_k[e,n]   = sum_d edge[e,d]*ht[n,d]*a_k[d]; select k(n,e); leaky; NEG
//   alpha      = softmax_e(T)
//   r[n,d]     = sum_e alpha[e,n] edge[e,d];  h_next=r; out (+)= r
// ---------------------------------------------------------------------------
template <bool WRITE_NEXT, bool ACC>
__global__ __launch_bounds__(512) void k_e2n(
    const float* __restrict__ h,    // (B,N,D)
    const float* __restrict__ s_c,  // (B,1,D)
    const float* __restrict__ Hm,   // (B,N,E)
    const float* __restrict__ a0,
    const float* __restrict__ a1,
    const float* __restrict__ a2,
    const float* __restrict__ edge, // (B,E,D)
    float* __restrict__ h_next,
    float* __restrict__ out)
{
    __shared__ float sh_ed[E_ * PAD];          // [e][d]
    __shared__ float sh_ht[EH * PAD];          // [ln][d]
    __shared__ float sh_S[E_ * SP];            // [e][ln]
    __shared__ unsigned char sh_k[E_ * KP];    // [e][ln]
    __shared__ float sh_a[3 * PAD];
    __shared__ float sh_inv[EH];

    const int b = blockIdx.y, nh = blockIdx.x;
    const int n_base = nh * EH;
    const int tid = threadIdx.x;

    for (int i4 = tid; i4 < E_ * D_ / 4; i4 += 512) {
        const float4 v = *reinterpret_cast<const float4*>(&edge[b * E_ * D_ + i4 * 4]);
        const int e = i4 >> 4, dq = i4 & 15;
        *reinterpret_cast<float4*>(&sh_ed[e * PAD + dq * 4]) = v;
    }
    if (tid < EH * D_ / 4) {
        const int i4 = tid;  // 800 threads needed; 512 → loop
    }
    for (int i4 = tid; i4 < EH * D_ / 4; i4 += 512) {
        const int ln = i4 >> 4, dq = i4 & 15;
        const float4 hv = *reinterpret_cast<const float4*>(&h[(b * N_ + n_base + ln) * D_ + dq * 4]);
        const float4 sc = *reinterpret_cast<const float4*>(&s_c[b * D_ + dq * 4]);
        *reinterpret_cast<float4*>(&sh_ht[ln * PAD + dq * 4]) =
            make_float4(hv.x + sc.x, hv.y + sc.y, hv.z + sc.z, hv.w + sc.w);
    }
    if (tid < 192) {
        const int k = tid >> 6, d = tid & 63;
        const float* ap = (k == 0) ? a0 : (k == 1) ? a1 : a2;
        sh_a[k * PAD + d] = ap[d];
    }
    // masks: coalesced over e; store transposed [e][ln]
    for (int i = tid; i < EH * E_; i += 512) {
        const int ln = i / E_, e = i % E_;
        sh_k[e * KP + ln] = (unsigned char)Hm[(b * N_ + n_base + ln) * E_ + e];
    }
    __syncthreads();

    // ---- score phase: outputs [e][ln], tile (4e,5n) ----
    if (tid < 250) {
        const int e0 = (tid / 10) * 4, ln0 = (tid % 10) * 5;
        float acc[3][4][5];
        #pragma unroll
        for (int k = 0; k < 3; ++k)
            #pragma unroll
            for (int i = 0; i < 4; ++i)
                #pragma unroll
                for (int j = 0; j < 5; ++j) acc[k][i][j] = 0.f;
        #pragma unroll
        for (int s = 0; s < 16; ++s) {
            const int d0 = s * 4;
            float4 edv[4], htv[5], av[3];
            #pragma unroll
            for (int i = 0; i < 4; ++i)
                edv[i] = *reinterpret_cast<const float4*>(&sh_ed[(e0 + i) * PAD + d0]);
            #pragma unroll
            for (int j = 0; j < 5; ++j)
                htv[j] = *reinterpret_cast<const float4*>(&sh_ht[(ln0 + j) * PAD + d0]);
            #pragma unroll
            for (int k = 0; k < 3; ++k)
                av[k] = *reinterpret_cast<const float4*>(&sh_a[k * PAD + d0]);
            #pragma unroll
            for (int k = 0; k < 3; ++k)
                #pragma unroll
                for (int j = 0; j < 5; ++j) {
                    const float wx = htv[j].x * av[k].x, wy = htv[j].y * av[k].y;
                    const float wz = htv[j].z * av[k].z, ww = htv[j].w * av[k].w;
                    #pragma unroll
                    for (int i = 0; i < 4; ++i)
                        acc[k][i][j] += edv[i].x * wx + edv[i].y * wy + edv[i].z * wz + edv[i].w * ww;
                }
        }
        #pragma unroll
        for (int i = 0; i < 4; ++i)
            #pragma unroll
            for (int j = 0; j < 5; ++j) {
                const int kk = sh_k[(e0 + i) * KP + ln0 + j];
                const float v = (kk == 1) ? acc[0][i][j] : (kk == 2) ? acc[1][i][j] : acc[2][i][j];
                const float lv = (v >= 0.f) ? v : LALPHA * v;
                sh_S[(e0 + i) * SP + ln0 + j] = (kk == 0) ? NEGV : lv;
            }
    }
    __syncthreads();

    // ---- softmax over e (rows), per ln column ----
    if (tid < 400) {
        const int ln = tid >> 3, g = tid & 7;
        float mx = -INFINITY;
        for (int e = g; e < E_; e += 8) mx = fmaxf(mx, sh_S[e * SP + ln]);
        mx = fmaxf(mx, __shfl_xor(mx, 1));
        mx = fmaxf(mx, __shfl_xor(mx, 2));
        mx = fmaxf(mx, __shfl_xor(mx, 4));
        float sum = 0.f;
        for (int e = g; e < E_; e += 8) {
            const float p = __expf(sh_S[e * SP + ln] - mx);
            sh_S[e * SP + ln] = p;
            sum += p;
        }
        sum += __shfl_xor(sum, 1);
        sum += __shfl_xor(sum, 2);
        sum += __shfl_xor(sum, 4);
        if (g == 0) sh_inv[ln] = 1.f / sum;
    }
    __syncthreads();

    // ---- result: r[ln,d] = inv[ln]*sum_e P[e,ln] ed[e,d]; tile (4n,8d), e-split 4 ----
    if (tid < 416) {
        const int ng = tid & 3, tile = tid >> 2;
        const int ln0 = (tile / 8) * 4, d0 = (tile & 7) * 8;
        float acc[4][8];
        #pragma unroll
        for (int i = 0; i < 4; ++i)
            #pragma unroll
            for (int j = 0; j < 8; ++j) acc[i][j] = 0.f;
        for (int e = ng * 25; e < ng * 25 + 25; ++e) {
            const float4 p = *reinterpret_cast<const float4*>(&sh_S[e * SP + ln0]);
            const float4 e0v = *reinterpret_cast<const float4*>(&sh_ed[e * PAD + d0]);
            const float4 e1v = *reinterpret_cast<const float4*>(&sh_ed[e * PAD + d0 + 4]);
            const float pv[4] = {p.x, p.y, p.z, p.w};
            const float ev[8] = {e0v.x, e0v.y, e0v.z, e0v.w, e1v.x, e1v.y, e1v.z, e1v.w};
            #pragma unroll
            for (int i = 0; i < 4; ++i)
                #pragma unroll
                for (int j = 0; j < 8; ++j) acc[i][j] += pv[i] * ev[j];
        }
        #pragma unroll
        for (int i = 0; i < 4; ++i)
            #pragma unroll
            for (int j = 0; j < 8; ++j) {
                float v = acc[i][j];
                v += __shfl_xor(v, 1);
                v += __shfl_xor(v, 2);
                acc[i][j] = v;
            }
        if (ng == 0) {
            #pragma unroll
            for (int i = 0; i < 4; ++i)
                if (ln0 + i < EH) {
                    const float inv = sh_inv[ln0 + i];
                    float r[8];
                    #pragma unroll
                    for (int j = 0; j < 8; ++j) r[j] = acc[i][j] * inv;
                    const int idx = (b * N_ + n_base + ln0 + i) * D_ + d0;
                    if (WRITE_NEXT) {
                        *reinterpret_cast<float4*>(&h_next[idx]) = make_float4(r[0], r[1], r[2], r[3]);
                        *reinterpret_cast<float4*>(&h_next[idx + 4]) = make_float4(r[4], r[5], r[6], r[7]);
                    }
                    if (ACC) {
                        float4 o0 = *reinterpret_cast<const float4*>(&out[idx]);
                        float4 o1 = *reinterpret_cast<const float4*>(&out[idx + 4]);
                        *reinterpret_cast<float4*>(&out[idx]) =
                            make_float4(o0.x + r[0], o0.y + r[1], o0.z + r[2], o0.w + r[3]);
                        *reinterpret_cast<float4*>(&out[idx + 4]) =
                            make_float4(o1.x + r[4], o1.y + r[5], o1.z + r[6], o1.w + r[7]);
                    } else {
                        *reinterpret_cast<float4*>(&out[idx]) = make_float4(r[0], r[1], r[2], r[3]);
                        *reinterpret_cast<float4*>(&out[idx + 4]) = make_float4(r[4], r[5], r[6], r[7]);
                    }
                }
        }
    }
}

extern "C" void kernel_launch(void* const* d_in, const int* in_sizes, int n_in,
                              void* d_out, int out_size, void* d_ws, size_t ws_size,
                              hipStream_t stream) {
    const float* hidden = (const float*)d_in[0];
    const float* Hm     = (const float*)d_in[1];
    const float* s_c    = (const float*)d_in[2];
    const float* a10    = (const float*)d_in[3];
    const float* a11    = (const float*)d_in[4];
    const float* a12    = (const float*)d_in[5];
    const float* a20    = (const float*)d_in[6];
    const float* a21    = (const float*)d_in[7];
    const float* a22    = (const float*)d_in[8];
    float* out = (float*)d_out;

    float* edge  = (float*)d_ws;                 // B*E*D
    float* hnext = edge + (size_t)B_ * E_ * D_;  // B*N*D

    const dim3 grid(2, B_);

    // layer 1
    k_n2e<<<grid, 512, 0, stream>>>(hidden, Hm, a10, a11, a12, edge);
    k_e2n<true, false><<<grid, 512, 0, stream>>>(hidden, s_c, Hm, a20, a21, a22, edge, hnext, out);
    // layer 2
    k_n2e<<<grid, 512, 0, stream>>>(hnext, Hm, a10, a11, a12, edge);
    k_e2n<false, true><<<grid, 512, 0, stream>>>(hnext, s_c, Hm, a20, a21, a22, edge, nullptr, out);
}

// Round 3
// 195.007 us; speedup vs baseline: 20.1008x; 20.1008x over previous
//
#include <hip/hip_runtime.h>
#include <math.h>

#define B_ 128
#define N_ 100
#define E_ 100
#define D_ 64
#define EH 50        // half of e (or n) per block
#define PAD 68       // row pad (f32 words) for [*][D] tiles; 68%8==4 -> adjacent rows shift banks by 4
#define SP 52        // score/mask row pad (f32 words), mult of 4 for float4
#define KP 52        // u8 mask row pad
#define LALPHA 0.2f
#define NEGV -9e15f

__device__ __forceinline__ float4 ld4(const float* p) { return *reinterpret_cast<const float4*>(p); }
__device__ __forceinline__ void st4(float* p, float4 v) { *reinterpret_cast<float4*>(p) = v; }

// ---------------------------------------------------------------------------
// node -> edge. grid (2, B), 512 threads, 1 block/CU.
//   ec[e,d]  = sum_n (H>0) h[n,d];  eck[k] = ec * a_k
//   S[n,e]   = select_k( sum_d h[n,d]*eck[k][e,d] ), leaky, NEG
//   P        = softmax_n(S);  edge[e,d] = sum_n P[n,e] h[n,d]
// ---------------------------------------------------------------------------
__global__ __launch_bounds__(512, 2) void k_n2e(
    const float* __restrict__ h,   // (B,N,D)
    const float* __restrict__ Hm,  // (B,N,E)
    const float* __restrict__ a0,
    const float* __restrict__ a1,
    const float* __restrict__ a2,
    float* __restrict__ edge)      // (B,E,D)
{
    __shared__ float sh_h[N_ * PAD];            // 27.2 KB
    __shared__ float sh_eck[3 * EH * PAD];      // 40.8 KB
    __shared__ float sh_S[N_ * SP];             // 20.8 KB
    __shared__ float sh_m01[N_ * SP];           // 20.8 KB
    __shared__ unsigned char sh_k[N_ * KP];     //  5.2 KB
    __shared__ float sh_a[3 * PAD];
    __shared__ float sh_inv[EH];

    const int b = blockIdx.y;
    const int e_base = blockIdx.x * EH;
    const int tid = threadIdx.x;

    // ---- A: stage ----
    for (int i4 = tid; i4 < N_ * D_ / 4; i4 += 512) {
        const float4 v = ld4(&h[b * N_ * D_ + i4 * 4]);
        st4(&sh_h[(i4 >> 4) * PAD + (i4 & 15) * 4], v);
    }
    if (tid < 192) {
        const int k = tid >> 6, d = tid & 63;
        sh_a[k * PAD + d] = (k == 0 ? a0 : k == 1 ? a1 : a2)[d];
    }
    for (int i = tid; i < N_ * EH; i += 512) {
        const int n = i / EH, le = i % EH;
        const int kk = (int)Hm[(b * N_ + n) * E_ + e_base + le];
        sh_k[n * KP + le] = (unsigned char)kk;
        sh_m01[n * SP + le] = (kk > 0) ? 1.f : 0.f;
    }
    __syncthreads();

    // ---- B: ec -> eck. tile (4e,8d), 104 threads ----
    if (tid < 104) {
        const int eg = tid >> 3, dg = tid & 7;
        const int e0 = eg * 4, d0 = dg * 8;
        float acc[4][8];
        #pragma unroll
        for (int i = 0; i < 4; ++i)
            #pragma unroll
            for (int j = 0; j < 8; ++j) acc[i][j] = 0.f;
        #pragma unroll 4
        for (int n = 0; n < N_; ++n) {
            const float4 m  = ld4(&sh_m01[n * SP + e0]);
            const float4 h0 = ld4(&sh_h[n * PAD + d0]);
            const float4 h1 = ld4(&sh_h[n * PAD + d0 + 4]);
            const float mv[4] = {m.x, m.y, m.z, m.w};
            const float hv[8] = {h0.x, h0.y, h0.z, h0.w, h1.x, h1.y, h1.z, h1.w};
            #pragma unroll
            for (int i = 0; i < 4; ++i)
                #pragma unroll
                for (int j = 0; j < 8; ++j) acc[i][j] += mv[i] * hv[j];
        }
        #pragma unroll
        for (int k = 0; k < 3; ++k) {
            const float4 a0v = ld4(&sh_a[k * PAD + d0]);
            const float4 a1v = ld4(&sh_a[k * PAD + d0 + 4]);
            const float av[8] = {a0v.x, a0v.y, a0v.z, a0v.w, a1v.x, a1v.y, a1v.z, a1v.w};
            #pragma unroll
            for (int i = 0; i < 4; ++i)
                if (e0 + i < EH) {
                    float* dst = &sh_eck[(k * EH + e0 + i) * PAD + d0];
                    st4(dst,     make_float4(acc[i][0]*av[0], acc[i][1]*av[1], acc[i][2]*av[2], acc[i][3]*av[3]));
                    st4(dst + 4, make_float4(acc[i][4]*av[4], acc[i][5]*av[5], acc[i][6]*av[6], acc[i][7]*av[7]));
                }
        }
    }
    __syncthreads();

    // ---- C: scores. tile rows {ng+25i} x 5e, d split in halves; 500 threads ----
    if (tid < 500) {
        const int t2 = tid >> 1, dh = tid & 1;
        const int eg = t2 / 25, ng = t2 % 25;      // eg 0..9, ng 0..24
        const int e0 = eg * 5;
        float acc[3][4][5];
        #pragma unroll
        for (int k = 0; k < 3; ++k)
            #pragma unroll
            for (int i = 0; i < 4; ++i)
                #pragma unroll
                for (int j = 0; j < 5; ++j) acc[k][i][j] = 0.f;
        const int dbase = dh * 32;
        #pragma unroll 2
        for (int s = 0; s < 8; ++s) {
            const int d0 = dbase + s * 4;
            float4 hv[4];
            #pragma unroll
            for (int i = 0; i < 4; ++i) hv[i] = ld4(&sh_h[(ng + 25 * i) * PAD + d0]);
            #pragma unroll
            for (int k = 0; k < 3; ++k)
                #pragma unroll
                for (int j = 0; j < 5; ++j) {
                    const float4 w = ld4(&sh_eck[(k * EH + e0 + j) * PAD + d0]);
                    #pragma unroll
                    for (int i = 0; i < 4; ++i)
                        acc[k][i][j] += hv[i].x * w.x + hv[i].y * w.y + hv[i].z * w.z + hv[i].w * w.w;
                }
        }
        #pragma unroll
        for (int k = 0; k < 3; ++k)
            #pragma unroll
            for (int i = 0; i < 4; ++i)
                #pragma unroll
                for (int j = 0; j < 5; ++j)
                    acc[k][i][j] += __shfl_xor(acc[k][i][j], 1);
        #define EPI_N2E(I) { \
            _Pragma("unroll") \
            for (int j = 0; j < 5; ++j) { \
                const int kk = sh_k[(ng + 25 * (I)) * KP + e0 + j]; \
                const float v = (kk == 1) ? acc[0][I][j] : (kk == 2) ? acc[1][I][j] : acc[2][I][j]; \
                const float lv = (v >= 0.f) ? v : LALPHA * v; \
                sh_S[(ng + 25 * (I)) * SP + e0 + j] = kk ? lv : NEGV; } }
        if (dh == 0) { EPI_N2E(0); EPI_N2E(1); } else { EPI_N2E(2); EPI_N2E(3); }
        #undef EPI_N2E
    }
    __syncthreads();

    // ---- D: softmax over n per e-column; 8 lanes/column ----
    if (tid < 400) {
        const int le = tid >> 3, g = tid & 7;
        float mx = -INFINITY;
        for (int n = g; n < N_; n += 8) mx = fmaxf(mx, sh_S[n * SP + le]);
        mx = fmaxf(mx, __shfl_xor(mx, 1));
        mx = fmaxf(mx, __shfl_xor(mx, 2));
        mx = fmaxf(mx, __shfl_xor(mx, 4));
        float sum = 0.f;
        for (int n = g; n < N_; n += 8) {
            const float p = __expf(sh_S[n * SP + le] - mx);
            sh_S[n * SP + le] = p;
            sum += p;
        }
        sum += __shfl_xor(sum, 1);
        sum += __shfl_xor(sum, 2);
        sum += __shfl_xor(sum, 4);
        if (g == 0) sh_inv[le] = 1.f / sum;
    }
    __syncthreads();

    // ---- E: edge[e,d] = inv[e] * sum_n P[n,e] h[n,d]; tile (4e,8d), 104 threads ----
    if (tid < 104) {
        const int eg = tid >> 3, dg = tid & 7;
        const int e0 = eg * 4, d0 = dg * 8;
        float acc[4][8];
        #pragma unroll
        for (int i = 0; i < 4; ++i)
            #pragma unroll
            for (int j = 0; j < 8; ++j) acc[i][j] = 0.f;
        #pragma unroll 4
        for (int n = 0; n < N_; ++n) {
            const float4 p  = ld4(&sh_S[n * SP + e0]);
            const float4 h0 = ld4(&sh_h[n * PAD + d0]);
            const float4 h1 = ld4(&sh_h[n * PAD + d0 + 4]);
            const float pv[4] = {p.x, p.y, p.z, p.w};
            const float hv[8] = {h0.x, h0.y, h0.z, h0.w, h1.x, h1.y, h1.z, h1.w};
            #pragma unroll
            for (int i = 0; i < 4; ++i)
                #pragma unroll
                for (int j = 0; j < 8; ++j) acc[i][j] += pv[i] * hv[j];
        }
        #pragma unroll
        for (int i = 0; i < 4; ++i)
            if (e0 + i < EH) {
                const float inv = sh_inv[e0 + i];
                float* dst = &edge[(b * E_ + e_base + e0 + i) * D_ + d0];
                st4(dst,     make_float4(acc[i][0]*inv, acc[i][1]*inv, acc[i][2]*inv, acc[i][3]*inv));
                st4(dst + 4, make_float4(acc[i][4]*inv, acc[i][5]*inv, acc[i][6]*inv, acc[i][7]*inv));
            }
    }
}

// ---------------------------------------------------------------------------
// edge -> node. grid (2, B), 512 threads.
//   htk[k][n,d] = (h[n,d]+s_c[d]) * a_k[d]   (n in this block's half)
//   S[e,n] = select_k( sum_d ed[e,d]*htk[k][n,d] ), leaky, NEG
//   P = softmax_e(S);  r[n,d] = sum_e P[e,n] ed[e,d];  h_next = r; out (+)= r
// ---------------------------------------------------------------------------
template <bool WRITE_NEXT, bool ACC>
__global__ __launch_bounds__(512, 2) void k_e2n(
    const float* __restrict__ h,    // (B,N,D)
    const float* __restrict__ s_c,  // (B,1,D)
    const float* __restrict__ Hm,   // (B,N,E)
    const float* __restrict__ a0,
    const float* __restrict__ a1,
    const float* __restrict__ a2,
    const float* __restrict__ edge, // (B,E,D)
    float* __restrict__ h_next,
    float* __restrict__ out)
{
    __shared__ float sh_ed[E_ * PAD];           // 27.2 KB
    __shared__ float sh_htk[3 * EH * PAD];      // 40.8 KB
    __shared__ float sh_S[E_ * SP];             // 20.8 KB
    __shared__ unsigned char sh_k[E_ * KP];     //  5.2 KB  [e][ln]
    __shared__ float sh_inv[EH];

    const int b = blockIdx.y;
    const int n_base = blockIdx.x * EH;
    const int tid = threadIdx.x;

    // ---- A: stage ----
    for (int i4 = tid; i4 < E_ * D_ / 4; i4 += 512) {
        const float4 v = ld4(&edge[b * E_ * D_ + i4 * 4]);
        st4(&sh_ed[(i4 >> 4) * PAD + (i4 & 15) * 4], v);
    }
    for (int i4 = tid; i4 < EH * D_ / 4; i4 += 512) {
        const int ln = i4 >> 4, dq = (i4 & 15) * 4;
        const float4 hv = ld4(&h[(b * N_ + n_base + ln) * D_ + dq]);
        const float4 sc = ld4(&s_c[b * D_ + dq]);
        const float4 t = make_float4(hv.x + sc.x, hv.y + sc.y, hv.z + sc.z, hv.w + sc.w);
        const float4 av0 = ld4(&a0[dq]), av1 = ld4(&a1[dq]), av2 = ld4(&a2[dq]);
        st4(&sh_htk[(0 * EH + ln) * PAD + dq], make_float4(t.x*av0.x, t.y*av0.y, t.z*av0.z, t.w*av0.w));
        st4(&sh_htk[(1 * EH + ln) * PAD + dq], make_float4(t.x*av1.x, t.y*av1.y, t.z*av1.z, t.w*av1.w));
        st4(&sh_htk[(2 * EH + ln) * PAD + dq], make_float4(t.x*av2.x, t.y*av2.y, t.z*av2.z, t.w*av2.w));
    }
    for (int i = tid; i < EH * E_; i += 512) {
        const int ln = i / E_, e = i % E_;
        sh_k[e * KP + ln] = (unsigned char)(int)Hm[(b * N_ + n_base + ln) * E_ + e];
    }
    __syncthreads();

    // ---- C: scores S[e,ln]; tile rows {eg+25i} x 5ln, d-halves; 500 threads ----
    if (tid < 500) {
        const int t2 = tid >> 1, dh = tid & 1;
        const int lg = t2 / 25, eg = t2 % 25;
        const int ln0 = lg * 5;
        float acc[3][4][5];
        #pragma unroll
        for (int k = 0; k < 3; ++k)
            #pragma unroll
            for (int i = 0; i < 4; ++i)
                #pragma unroll
                for (int j = 0; j < 5; ++j) acc[k][i][j] = 0.f;
        const int dbase = dh * 32;
        #pragma unroll 2
        for (int s = 0; s < 8; ++s) {
            const int d0 = dbase + s * 4;
            float4 ev[4];
            #pragma unroll
            for (int i = 0; i < 4; ++i) ev[i] = ld4(&sh_ed[(eg + 25 * i) * PAD + d0]);
            #pragma unroll
            for (int k = 0; k < 3; ++k)
                #pragma unroll
                for (int j = 0; j < 5; ++j) {
                    const float4 w = ld4(&sh_htk[(k * EH + ln0 + j) * PAD + d0]);
                    #pragma unroll
                    for (int i = 0; i < 4; ++i)
                        acc[k][i][j] += ev[i].x * w.x + ev[i].y * w.y + ev[i].z * w.z + ev[i].w * w.w;
                }
        }
        #pragma unroll
        for (int k = 0; k < 3; ++k)
            #pragma unroll
            for (int i = 0; i < 4; ++i)
                #pragma unroll
                for (int j = 0; j < 5; ++j)
                    acc[k][i][j] += __shfl_xor(acc[k][i][j], 1);
        #define EPI_E2N(I) { \
            _Pragma("unroll") \
            for (int j = 0; j < 5; ++j) { \
                const int kk = sh_k[(eg + 25 * (I)) * KP + ln0 + j]; \
                const float v = (kk == 1) ? acc[0][I][j] : (kk == 2) ? acc[1][I][j] : acc[2][I][j]; \
                const float lv = (v >= 0.f) ? v : LALPHA * v; \
                sh_S[(eg + 25 * (I)) * SP + ln0 + j] = kk ? lv : NEGV; } }
        if (dh == 0) { EPI_E2N(0); EPI_E2N(1); } else { EPI_E2N(2); EPI_E2N(3); }
        #undef EPI_E2N
    }
    __syncthreads();

    // ---- D: softmax over e per ln-column ----
    if (tid < 400) {
        const int ln = tid >> 3, g = tid & 7;
        float mx = -INFINITY;
        for (int e = g; e < E_; e += 8) mx = fmaxf(mx, sh_S[e * SP + ln]);
        mx = fmaxf(mx, __shfl_xor(mx, 1));
        mx = fmaxf(mx, __shfl_xor(mx, 2));
        mx = fmaxf(mx, __shfl_xor(mx, 4));
        float sum = 0.f;
        for (int e = g; e < E_; e += 8) {
            const float p = __expf(sh_S[e * SP + ln] - mx);
            sh_S[e * SP + ln] = p;
            sum += p;
        }
        sum += __shfl_xor(sum, 1);
        sum += __shfl_xor(sum, 2);
        sum += __shfl_xor(sum, 4);
        if (g == 0) sh_inv[ln] = 1.f / sum;
    }
    __syncthreads();

    // ---- E: r[ln,d] = inv[ln] * sum_e P[e,ln] ed[e,d]; tile (4ln,8d), 104 threads ----
    if (tid < 104) {
        const int lg = tid >> 3, dg = tid & 7;
        const int ln0 = lg * 4, d0 = dg * 8;
        float acc[4][8];
        #pragma unroll
        for (int i = 0; i < 4; ++i)
            #pragma unroll
            for (int j = 0; j < 8; ++j) acc[i][j] = 0.f;
        #pragma unroll 4
        for (int e = 0; e < E_; ++e) {
            const float4 p  = ld4(&sh_S[e * SP + ln0]);
            const float4 e0v = ld4(&sh_ed[e * PAD + d0]);
            const float4 e1v = ld4(&sh_ed[e * PAD + d0 + 4]);
            const float pv[4] = {p.x, p.y, p.z, p.w};
            const float ev[8] = {e0v.x, e0v.y, e0v.z, e0v.w, e1v.x, e1v.y, e1v.z, e1v.w};
            #pragma unroll
            for (int i = 0; i < 4; ++i)
                #pragma unroll
                for (int j = 0; j < 8; ++j) acc[i][j] += pv[i] * ev[j];
        }
        #pragma unroll
        for (int i = 0; i < 4; ++i)
            if (ln0 + i < EH) {
                const float inv = sh_inv[ln0 + i];
                float r[8];
                #pragma unroll
                for (int j = 0; j < 8; ++j) r[j] = acc[i][j] * inv;
                const int idx = (b * N_ + n_base + ln0 + i) * D_ + d0;
                if (WRITE_NEXT) {
                    st4(&h_next[idx],     make_float4(r[0], r[1], r[2], r[3]));
                    st4(&h_next[idx + 4], make_float4(r[4], r[5], r[6], r[7]));
                }
                if (ACC) {
                    const float4 o0 = ld4(&out[idx]);
                    const float4 o1 = ld4(&out[idx + 4]);
                    st4(&out[idx],     make_float4(o0.x + r[0], o0.y + r[1], o0.z + r[2], o0.w + r[3]));
                    st4(&out[idx + 4], make_float4(o1.x + r[4], o1.y + r[5], o1.z + r[6], o1.w + r[7]));
                } else {
                    st4(&out[idx],     make_float4(r[0], r[1], r[2], r[3]));
                    st4(&out[idx + 4], make_float4(r[4], r[5], r[6], r[7]));
                }
            }
    }
}

extern "C" void kernel_launch(void* const* d_in, const int* in_sizes, int n_in,
                              void* d_out, int out_size, void* d_ws, size_t ws_size,
                              hipStream_t stream) {
    const float* hidden = (const float*)d_in[0];
    const float* Hm     = (const float*)d_in[1];
    const float* s_c    = (const float*)d_in[2];
    const float* a10    = (const float*)d_in[3];
    const float* a11    = (const float*)d_in[4];
    const float* a12    = (const float*)d_in[5];
    const float* a20    = (const float*)d_in[6];
    const float* a21    = (const float*)d_in[7];
    const float* a22    = (const float*)d_in[8];
    float* out = (float*)d_out;

    float* edge  = (float*)d_ws;                 // B*E*D
    float* hnext = edge + (size_t)B_ * E_ * D_;  // B*N*D

    const dim3 grid(2, B_);

    // layer 1
    k_n2e<<<grid, 512, 0, stream>>>(hidden, Hm, a10, a11, a12, edge);
    k_e2n<true, false><<<grid, 512, 0, stream>>>(hidden, s_c, Hm, a20, a21, a22, edge, hnext, out);
    // layer 2
    k_n2e<<<grid, 512, 0, stream>>>(hnext, Hm, a10, a11, a12, edge);
    k_e2n<false, true><<<grid, 512, 0, stream>>>(hnext, s_c, Hm, a20, a21, a22, edge, nullptr, out);
}

// Round 4
// 180.438 us; speedup vs baseline: 21.7237x; 1.0807x over previous
//
#include <hip/hip_runtime.h>
#include <math.h>

#define B_ 128
#define N_ 100
#define E_ 100
#define D_ 64
#define EH 50        // half of e (or n) per block
#define PAD 68       // row pad (f32 words) for [*][D] tiles
#define SP 52        // score/mask row pad (f32 words), mult of 4
#define KP 52        // u8 mask row pad
#define LALPHA 0.2f
#define NEGV -9e15f

__device__ __forceinline__ float4 ld4(const float* p) { return *reinterpret_cast<const float4*>(p); }
__device__ __forceinline__ void st4(float* p, float4 v) { *reinterpret_cast<float4*>(p) = v; }
__device__ __forceinline__ float dot4(float4 a, float4 b) {
    return a.x * b.x + a.y * b.y + a.z * b.z + a.w * b.w;
}

// ---------------------------------------------------------------------------
// node -> edge. grid (2, B), 512 threads.
//   ec[e,d]  = sum_n (H>0) h[n,d]
//   S[n,e]   = select_k( sum_d h[n,d]*ec[e,d]*a_k[d] ), leaky, NEG
//   P        = softmax_n(S);  edge[e,d] = sum_n P[n,e] h[n,d]
// LDS ~67.8 KB.  sh_S doubles as m01 (mask floats) before phase C.
// ---------------------------------------------------------------------------
__global__ __launch_bounds__(512, 2) void k_n2e(
    const float* __restrict__ h,   // (B,N,D)
    const float* __restrict__ Hm,  // (B,N,E)
    const float* __restrict__ a0,
    const float* __restrict__ a1,
    const float* __restrict__ a2,
    float* __restrict__ edge)      // (B,E,D)
{
    __shared__ float sh_h[N_ * PAD];          // 27.2 KB
    __shared__ float sh_ec[EH * PAD];         // 13.6 KB
    __shared__ float sh_S[N_ * SP];           // 20.8 KB (m01 -> scores -> P)
    __shared__ unsigned char sh_k[N_ * KP];   //  5.2 KB
    __shared__ float sh_a[3 * PAD];           //  0.8 KB
    __shared__ float sh_inv[EH];

    const int b = blockIdx.y;
    const int e_base = blockIdx.x * EH;
    const int tid = threadIdx.x;

    // ---- A: stage ----
    for (int i4 = tid; i4 < N_ * D_ / 4; i4 += 512) {
        const float4 v = ld4(&h[b * N_ * D_ + i4 * 4]);
        st4(&sh_h[(i4 >> 4) * PAD + (i4 & 15) * 4], v);
    }
    if (tid < 192) {
        const int k = tid >> 6, d = tid & 63;
        sh_a[k * PAD + d] = (k == 0 ? a0 : k == 1 ? a1 : a2)[d];
    }
    for (int i = tid; i < N_ * EH; i += 512) {
        const int n = i / EH, le = i % EH;
        const int kk = (int)Hm[(b * N_ + n) * E_ + e_base + le];
        sh_k[n * KP + le] = (unsigned char)kk;
        sh_S[n * SP + le] = (kk > 0) ? 1.f : 0.f;   // m01 (aliased)
    }
    __syncthreads();

    // ---- B: ec[e,d] = sum_n m01[n,e]*h[n,d]; tile (4e,8d), 4-way n-split; 416 thr ----
    if (tid < 416) {
        const int ng = tid & 3, dg = (tid >> 2) & 7, eg = tid >> 5;  // eg 0..12
        const int e0 = eg * 4, d0 = dg * 8;
        float acc[4][8];
        #pragma unroll
        for (int i = 0; i < 4; ++i)
            #pragma unroll
            for (int j = 0; j < 8; ++j) acc[i][j] = 0.f;
        #pragma unroll 5
        for (int n = ng * 25; n < ng * 25 + 25; ++n) {
            const float4 m  = ld4(&sh_S[n * SP + e0]);
            const float4 h0 = ld4(&sh_h[n * PAD + d0]);
            const float4 h1 = ld4(&sh_h[n * PAD + d0 + 4]);
            const float mv[4] = {m.x, m.y, m.z, m.w};
            const float hv[8] = {h0.x, h0.y, h0.z, h0.w, h1.x, h1.y, h1.z, h1.w};
            #pragma unroll
            for (int i = 0; i < 4; ++i)
                #pragma unroll
                for (int j = 0; j < 8; ++j) acc[i][j] += mv[i] * hv[j];
        }
        #pragma unroll
        for (int i = 0; i < 4; ++i)
            #pragma unroll
            for (int j = 0; j < 8; ++j) {
                float v = acc[i][j];
                v += __shfl_xor(v, 1);
                v += __shfl_xor(v, 2);
                acc[i][j] = v;
            }
        if (ng == 0) {
            #pragma unroll
            for (int i = 0; i < 4; ++i)
                if (e0 + i < EH) {
                    float* dst = &sh_ec[(e0 + i) * PAD + d0];
                    st4(dst,     make_float4(acc[i][0], acc[i][1], acc[i][2], acc[i][3]));
                    st4(dst + 4, make_float4(acc[i][4], acc[i][5], acc[i][6], acc[i][7]));
                }
        }
    }
    __syncthreads();

    // ---- C: scores; tile rows {ng+25i} x 5e, d halves, on-the-fly a-fold; 500 thr ----
    if (tid < 500) {
        const int t2 = tid >> 1, dh = tid & 1;
        const int eg = t2 / 25, ng = t2 % 25;     // eg 0..9
        const int e0 = eg * 5;
        float acc[3][4][5];
        #pragma unroll
        for (int k = 0; k < 3; ++k)
            #pragma unroll
            for (int i = 0; i < 4; ++i)
                #pragma unroll
                for (int j = 0; j < 5; ++j) acc[k][i][j] = 0.f;
        const int dbase = dh * 32;
        #pragma unroll 2
        for (int s = 0; s < 8; ++s) {
            const int d0 = dbase + s * 4;
            float4 hv[4], av[3];
            #pragma unroll
            for (int i = 0; i < 4; ++i) hv[i] = ld4(&sh_h[(ng + 25 * i) * PAD + d0]);
            #pragma unroll
            for (int k = 0; k < 3; ++k) av[k] = ld4(&sh_a[k * PAD + d0]);
            #pragma unroll
            for (int j = 0; j < 5; ++j) {
                const float4 ev = ld4(&sh_ec[(e0 + j) * PAD + d0]);
                #pragma unroll
                for (int k = 0; k < 3; ++k) {
                    const float4 w = make_float4(ev.x * av[k].x, ev.y * av[k].y,
                                                 ev.z * av[k].z, ev.w * av[k].w);
                    #pragma unroll
                    for (int i = 0; i < 4; ++i) acc[k][i][j] += dot4(hv[i], w);
                }
            }
        }
        #pragma unroll
        for (int k = 0; k < 3; ++k)
            #pragma unroll
            for (int i = 0; i < 4; ++i)
                #pragma unroll
                for (int j = 0; j < 5; ++j)
                    acc[k][i][j] += __shfl_xor(acc[k][i][j], 1);
        #define EPI_N2E(I) { \
            _Pragma("unroll") \
            for (int j = 0; j < 5; ++j) { \
                const int kk = sh_k[(ng + 25 * (I)) * KP + e0 + j]; \
                const float v = (kk == 1) ? acc[0][I][j] : (kk == 2) ? acc[1][I][j] : acc[2][I][j]; \
                const float lv = (v >= 0.f) ? v : LALPHA * v; \
                sh_S[(ng + 25 * (I)) * SP + e0 + j] = kk ? lv : NEGV; } }
        if (dh == 0) { EPI_N2E(0); EPI_N2E(1); } else { EPI_N2E(2); EPI_N2E(3); }
        #undef EPI_N2E
    }
    __syncthreads();

    // ---- D: softmax over n per e-column; 8 lanes/column; 400 thr ----
    if (tid < 400) {
        const int le = tid >> 3, g = tid & 7;
        float mx = -INFINITY;
        for (int n = g; n < N_; n += 8) mx = fmaxf(mx, sh_S[n * SP + le]);
        mx = fmaxf(mx, __shfl_xor(mx, 1));
        mx = fmaxf(mx, __shfl_xor(mx, 2));
        mx = fmaxf(mx, __shfl_xor(mx, 4));
        float sum = 0.f;
        for (int n = g; n < N_; n += 8) {
            const float p = __expf(sh_S[n * SP + le] - mx);
            sh_S[n * SP + le] = p;
            sum += p;
        }
        sum += __shfl_xor(sum, 1);
        sum += __shfl_xor(sum, 2);
        sum += __shfl_xor(sum, 4);
        if (g == 0) sh_inv[le] = 1.f / sum;
    }
    __syncthreads();

    // ---- E: edge[e,d] = inv[e]*sum_n P[n,e] h[n,d]; tile (4e,8d), n-split-4; 416 thr ----
    if (tid < 416) {
        const int ng = tid & 3, dg = (tid >> 2) & 7, eg = tid >> 5;
        const int e0 = eg * 4, d0 = dg * 8;
        float acc[4][8];
        #pragma unroll
        for (int i = 0; i < 4; ++i)
            #pragma unroll
            for (int j = 0; j < 8; ++j) acc[i][j] = 0.f;
        #pragma unroll 5
        for (int n = ng * 25; n < ng * 25 + 25; ++n) {
            const float4 p  = ld4(&sh_S[n * SP + e0]);
            const float4 h0 = ld4(&sh_h[n * PAD + d0]);
            const float4 h1 = ld4(&sh_h[n * PAD + d0 + 4]);
            const float pv[4] = {p.x, p.y, p.z, p.w};
            const float hv[8] = {h0.x, h0.y, h0.z, h0.w, h1.x, h1.y, h1.z, h1.w};
            #pragma unroll
            for (int i = 0; i < 4; ++i)
                #pragma unroll
                for (int j = 0; j < 8; ++j) acc[i][j] += pv[i] * hv[j];
        }
        #pragma unroll
        for (int i = 0; i < 4; ++i)
            #pragma unroll
            for (int j = 0; j < 8; ++j) {
                float v = acc[i][j];
                v += __shfl_xor(v, 1);
                v += __shfl_xor(v, 2);
                acc[i][j] = v;
            }
        if (ng == 0) {
            #pragma unroll
            for (int i = 0; i < 4; ++i)
                if (e0 + i < EH) {
                    const float inv = sh_inv[e0 + i];
                    float* dst = &edge[(b * E_ + e_base + e0 + i) * D_ + d0];
                    st4(dst,     make_float4(acc[i][0]*inv, acc[i][1]*inv, acc[i][2]*inv, acc[i][3]*inv));
                    st4(dst + 4, make_float4(acc[i][4]*inv, acc[i][5]*inv, acc[i][6]*inv, acc[i][7]*inv));
                }
        }
    }
}

// ---------------------------------------------------------------------------
// edge -> node. grid (2, B), 512 threads.
//   ht[n,d] = h[n,d] + s_c[d]  (n in this block's half)
//   S[e,n]  = select_k( sum_d ed[e,d]*ht[n,d]*a_k[d] ), leaky, NEG
//   P = softmax_e(S);  r[n,d] = sum_e P[e,n] ed[e,d];  h_next = r; out (+)= r
// LDS ~67.8 KB.
// ---------------------------------------------------------------------------
template <bool WRITE_NEXT, bool ACC>
__global__ __launch_bounds__(512, 2) void k_e2n(
    const float* __restrict__ h,    // (B,N,D)
    const float* __restrict__ s_c,  // (B,1,D)
    const float* __restrict__ Hm,   // (B,N,E)
    const float* __restrict__ a0,
    const float* __restrict__ a1,
    const float* __restrict__ a2,
    const float* __restrict__ edge, // (B,E,D)
    float* __restrict__ h_next,
    float* __restrict__ out)
{
    __shared__ float sh_ed[E_ * PAD];          // 27.2 KB
    __shared__ float sh_ht[EH * PAD];          // 13.6 KB
    __shared__ float sh_S[E_ * SP];            // 20.8 KB
    __shared__ unsigned char sh_k[E_ * KP];    //  5.2 KB  [e][ln]
    __shared__ float sh_a[3 * PAD];            //  0.8 KB
    __shared__ float sh_inv[EH];

    const int b = blockIdx.y;
    const int n_base = blockIdx.x * EH;
    const int tid = threadIdx.x;

    // ---- A: stage ----
    for (int i4 = tid; i4 < E_ * D_ / 4; i4 += 512) {
        const float4 v = ld4(&edge[b * E_ * D_ + i4 * 4]);
        st4(&sh_ed[(i4 >> 4) * PAD + (i4 & 15) * 4], v);
    }
    for (int i4 = tid; i4 < EH * D_ / 4; i4 += 512) {
        const int ln = i4 >> 4, dq = (i4 & 15) * 4;
        const float4 hv = ld4(&h[(b * N_ + n_base + ln) * D_ + dq]);
        const float4 sc = ld4(&s_c[b * D_ + dq]);
        st4(&sh_ht[ln * PAD + dq], make_float4(hv.x + sc.x, hv.y + sc.y, hv.z + sc.z, hv.w + sc.w));
    }
    if (tid < 192) {
        const int k = tid >> 6, d = tid & 63;
        sh_a[k * PAD + d] = (k == 0 ? a0 : k == 1 ? a1 : a2)[d];
    }
    for (int i = tid; i < EH * E_; i += 512) {
        const int ln = i / E_, e = i % E_;
        sh_k[e * KP + ln] = (unsigned char)(int)Hm[(b * N_ + n_base + ln) * E_ + e];
    }
    __syncthreads();

    // ---- C: scores S[e,ln]; tile rows {eg+25i} x 5ln, d halves, on-the-fly fold; 500 thr ----
    if (tid < 500) {
        const int t2 = tid >> 1, dh = tid & 1;
        const int lg = t2 / 25, eg = t2 % 25;
        const int ln0 = lg * 5;
        float acc[3][4][5];
        #pragma unroll
        for (int k = 0; k < 3; ++k)
            #pragma unroll
            for (int i = 0; i < 4; ++i)
                #pragma unroll
                for (int j = 0; j < 5; ++j) acc[k][i][j] = 0.f;
        const int dbase = dh * 32;
        #pragma unroll 2
        for (int s = 0; s < 8; ++s) {
            const int d0 = dbase + s * 4;
            float4 ev[4], av[3];
            #pragma unroll
            for (int i = 0; i < 4; ++i) ev[i] = ld4(&sh_ed[(eg + 25 * i) * PAD + d0]);
            #pragma unroll
            for (int k = 0; k < 3; ++k) av[k] = ld4(&sh_a[k * PAD + d0]);
            #pragma unroll
            for (int j = 0; j < 5; ++j) {
                const float4 tv = ld4(&sh_ht[(ln0 + j) * PAD + d0]);
                #pragma unroll
                for (int k = 0; k < 3; ++k) {
                    const float4 w = make_float4(tv.x * av[k].x, tv.y * av[k].y,
                                                 tv.z * av[k].z, tv.w * av[k].w);
                    #pragma unroll
                    for (int i = 0; i < 4; ++i) acc[k][i][j] += dot4(ev[i], w);
                }
            }
        }
        #pragma unroll
        for (int k = 0; k < 3; ++k)
            #pragma unroll
            for (int i = 0; i < 4; ++i)
                #pragma unroll
                for (int j = 0; j < 5; ++j)
                    acc[k][i][j] += __shfl_xor(acc[k][i][j], 1);
        #define EPI_E2N(I) { \
            _Pragma("unroll") \
            for (int j = 0; j < 5; ++j) { \
                const int kk = sh_k[(eg + 25 * (I)) * KP + ln0 + j]; \
                const float v = (kk == 1) ? acc[0][I][j] : (kk == 2) ? acc[1][I][j] : acc[2][I][j]; \
                const float lv = (v >= 0.f) ? v : LALPHA * v; \
                sh_S[(eg + 25 * (I)) * SP + ln0 + j] = kk ? lv : NEGV; } }
        if (dh == 0) { EPI_E2N(0); EPI_E2N(1); } else { EPI_E2N(2); EPI_E2N(3); }
        #undef EPI_E2N
    }
    __syncthreads();

    // ---- D: softmax over e per ln-column; 400 thr ----
    if (tid < 400) {
        const int ln = tid >> 3, g = tid & 7;
        float mx = -INFINITY;
        for (int e = g; e < E_; e += 8) mx = fmaxf(mx, sh_S[e * SP + ln]);
        mx = fmaxf(mx, __shfl_xor(mx, 1));
        mx = fmaxf(mx, __shfl_xor(mx, 2));
        mx = fmaxf(mx, __shfl_xor(mx, 4));
        float sum = 0.f;
        for (int e = g; e < E_; e += 8) {
            const float p = __expf(sh_S[e * SP + ln] - mx);
            sh_S[e * SP + ln] = p;
            sum += p;
        }
        sum += __shfl_xor(sum, 1);
        sum += __shfl_xor(sum, 2);
        sum += __shfl_xor(sum, 4);
        if (g == 0) sh_inv[ln] = 1.f / sum;
    }
    __syncthreads();

    // ---- R: r[ln,d] = inv[ln]*sum_e P[e,ln] ed[e,d]; tile (4ln,8d), e-split-4; 416 thr ----
    if (tid < 416) {
        const int eg = tid & 3, dg = (tid >> 2) & 7, lg = tid >> 5;  // lg 0..12
        const int ln0 = lg * 4, d0 = dg * 8;
        float acc[4][8];
        #pragma unroll
        for (int i = 0; i < 4; ++i)
            #pragma unroll
            for (int j = 0; j < 8; ++j) acc[i][j] = 0.f;
        #pragma unroll 5
        for (int e = eg * 25; e < eg * 25 + 25; ++e) {
            const float4 p   = ld4(&sh_S[e * SP + ln0]);
            const float4 e0v = ld4(&sh_ed[e * PAD + d0]);
            const float4 e1v = ld4(&sh_ed[e * PAD + d0 + 4]);
            const float pv[4] = {p.x, p.y, p.z, p.w};
            const float ev[8] = {e0v.x, e0v.y, e0v.z, e0v.w, e1v.x, e1v.y, e1v.z, e1v.w};
            #pragma unroll
            for (int i = 0; i < 4; ++i)
                #pragma unroll
                for (int j = 0; j < 8; ++j) acc[i][j] += pv[i] * ev[j];
        }
        #pragma unroll
        for (int i = 0; i < 4; ++i)
            #pragma unroll
            for (int j = 0; j < 8; ++j) {
                float v = acc[i][j];
                v += __shfl_xor(v, 1);
                v += __shfl_xor(v, 2);
                acc[i][j] = v;
            }
        if (eg == 0) {
            #pragma unroll
            for (int i = 0; i < 4; ++i)
                if (ln0 + i < EH) {
                    const float inv = sh_inv[ln0 + i];
                    float r[8];
                    #pragma unroll
                    for (int j = 0; j < 8; ++j) r[j] = acc[i][j] * inv;
                    const int idx = (b * N_ + n_base + ln0 + i) * D_ + d0;
                    if (WRITE_NEXT) {
                        st4(&h_next[idx],     make_float4(r[0], r[1], r[2], r[3]));
                        st4(&h_next[idx + 4], make_float4(r[4], r[5], r[6], r[7]));
                    }
                    if (ACC) {
                        const float4 o0 = ld4(&out[idx]);
                        const float4 o1 = ld4(&out[idx + 4]);
                        st4(&out[idx],     make_float4(o0.x + r[0], o0.y + r[1], o0.z + r[2], o0.w + r[3]));
                        st4(&out[idx + 4], make_float4(o1.x + r[4], o1.y + r[5], o1.z + r[6], o1.w + r[7]));
                    } else {
                        st4(&out[idx],     make_float4(r[0], r[1], r[2], r[3]));
                        st4(&out[idx + 4], make_float4(r[4], r[5], r[6], r[7]));
                    }
                }
        }
    }
}

extern "C" void kernel_launch(void* const* d_in, const int* in_sizes, int n_in,
                              void* d_out, int out_size, void* d_ws, size_t ws_size,
                              hipStream_t stream) {
    const float* hidden = (const float*)d_in[0];
    const float* Hm     = (const float*)d_in[1];
    const float* s_c    = (const float*)d_in[2];
    const float* a10    = (const float*)d_in[3];
    const float* a11    = (const float*)d_in[4];
    const float* a12    = (const float*)d_in[5];
    const float* a20    = (const float*)d_in[6];
    const float* a21    = (const float*)d_in[7];
    const float* a22    = (const float*)d_in[8];
    float* out = (float*)d_out;

    float* edge  = (float*)d_ws;                 // B*E*D
    float* hnext = edge + (size_t)B_ * E_ * D_;  // B*N*D

    const dim3 grid(2, B_);

    // layer 1
    k_n2e<<<grid, 512, 0, stream>>>(hidden, Hm, a10, a11, a12, edge);
    k_e2n<true, false><<<grid, 512, 0, stream>>>(hidden, s_c, Hm, a20, a21, a22, edge, hnext, out);
    // layer 2
    k_n2e<<<grid, 512, 0, stream>>>(hnext, Hm, a10, a11, a12, edge);
    k_e2n<false, true><<<grid, 512, 0, stream>>>(hnext, s_c, Hm, a20, a21, a22, edge, nullptr, out);
}